// Round 6
// baseline (16222.954 us; speedup 1.0000x reference)
//
#include <hip/hip_runtime.h>
#include <math.h>

typedef __attribute__((ext_vector_type(4))) float f32x4;
typedef __attribute__((ext_vector_type(8))) __bf16 bf16x8;
typedef __attribute__((ext_vector_type(4))) __bf16 bf16x4;
typedef __attribute__((ext_vector_type(4))) unsigned int u32x4;

#define DI __device__ __forceinline__

constexpr int Bd = 2, Sd = 2048, Vd = 32000, Ed = 512, Hd = 1024, MDd = 256, Pd = 4096, Wd = 128;
constexpr int BS = Bd * Sd;          // 4096 rows
constexpr int GBLK = 64;             // GRU blocks: 32 per batch group

DI float sigmoidf_(float x) { return 1.0f / (1.0f + expf(-x)); }

// ---------------------------------------------------------------------------
// Generic GEMM: C[M,N] = epi( A[M,K] * Wt[N,K]^T + bias )
// EPI 0: C = acc + bias
// EPI 1: C = (relu(acc + bias))^2
// EPI 3: atomicAdd(C[r, untied[c]], acc + (1 + gate[r]*ms) * bias[c])
// ---------------------------------------------------------------------------
template<int EPI>
__global__ __launch_bounds__(256) void gemm_bt(
    const float* __restrict__ A, const float* __restrict__ Wt,
    const float* __restrict__ bias, float* __restrict__ C,
    int M, int N, int K, int ldc,
    const float* __restrict__ gate, const float* __restrict__ msp,
    const int* __restrict__ untied)
{
  __shared__ __bf16 As[128][40];   // +8 pad: 80B row stride, 16B-aligned
  __shared__ __bf16 Bs[128][40];
  const int tid  = threadIdx.x;
  const int lane = tid & 63, wv = tid >> 6;
  const int m0 = blockIdx.y * 128, n0 = blockIdx.x * 128;
  const int wrow = (wv >> 1) * 64, wcol = (wv & 1) * 64;

  f32x4 acc[4][4] = {};

  const int sr  = tid >> 3;          // 0..31
  const int sc4 = (tid & 7) << 2;    // 0..28 step 4
  const int nk  = K >> 5;

  for (int kt = 0; kt < nk; ++kt) {
    const int k0 = kt << 5;
    __syncthreads();
    #pragma unroll
    for (int i = 0; i < 4; ++i) {
      const int r = sr + 32 * i;
      f32x4 av = *reinterpret_cast<const f32x4*>(A  + (size_t)(m0 + r) * K + k0 + sc4);
      f32x4 bv = *reinterpret_cast<const f32x4*>(Wt + (size_t)(n0 + r) * K + k0 + sc4);
      bf16x4 ah, bh;
      ah.x = (__bf16)av.x; ah.y = (__bf16)av.y; ah.z = (__bf16)av.z; ah.w = (__bf16)av.w;
      bh.x = (__bf16)bv.x; bh.y = (__bf16)bv.y; bh.z = (__bf16)bv.z; bh.w = (__bf16)bv.w;
      *reinterpret_cast<bf16x4*>(&As[r][sc4]) = ah;
      *reinterpret_cast<bf16x4*>(&Bs[r][sc4]) = bh;
    }
    __syncthreads();

    bf16x8 af[4], bfr[4];
    #pragma unroll
    for (int t2 = 0; t2 < 4; ++t2) {
      af[t2]  = *reinterpret_cast<const bf16x8*>(&As[wrow + t2 * 16 + (lane & 15)][(lane >> 4) * 8]);
      bfr[t2] = *reinterpret_cast<const bf16x8*>(&Bs[wcol + t2 * 16 + (lane & 15)][(lane >> 4) * 8]);
    }
    #pragma unroll
    for (int mi = 0; mi < 4; ++mi)
      #pragma unroll
      for (int ni = 0; ni < 4; ++ni)
        acc[mi][ni] = __builtin_amdgcn_mfma_f32_16x16x32_bf16(af[mi], bfr[ni], acc[mi][ni], 0, 0, 0);
  }

  const float ms = (EPI == 3) ? msp[0] : 0.f;
  #pragma unroll
  for (int mi = 0; mi < 4; ++mi) {
    #pragma unroll
    for (int ni = 0; ni < 4; ++ni) {
      const int cc = n0 + wcol + ni * 16 + (lane & 15);
      const float bv = bias ? bias[cc] : 0.f;
      #pragma unroll
      for (int rg = 0; rg < 4; ++rg) {
        const int rr = m0 + wrow + mi * 16 + (lane >> 4) * 4 + rg;
        const float v = acc[mi][ni][rg];
        if (EPI == 0) {
          C[(size_t)rr * ldc + cc] = v + bv;
        } else if (EPI == 1) {
          float u = fmaxf(v + bv, 0.f);
          C[(size_t)rr * ldc + cc] = u * u;
        } else {
          float g = 1.f + gate[rr] * ms;
          atomicAdd(&C[(size_t)rr * ldc + untied[cc]], v + g * bv);
        }
      }
    }
  }
}

// Device-coherent 16B poll: sc0 (L1 bypass) + sc1 (L2 bypass) reads the
// coherence point where producers' relaxed agent atomic stores land.
DI void poll2_coherent(const unsigned long long* p, u32x4& a) {
  asm volatile("global_load_dwordx4 %0, %1, off sc0 sc1\n\t"
               "s_waitcnt vmcnt(0)"
               : "=&v"(a) : "v"(p) : "memory");
}

// ---------------------------------------------------------------------------
// Persistent GRU v6: 64 blocks x 512 threads, split into two independent
// groups of 32 (one per batch). Wave wv of group-block gb owns 4 contiguous
// h-indices j0..j0+3 of its batch; 12 w_hh rows live in registers (192 VGPR).
// Exchange per group: 1024 {tag,val} u64 slots, parity double-buffered.
// Producers: relaxed agent atomic stores. Consumers: ONE 16B sc0+sc1 load
// per thread per poll round (4x fewer poll ops than v5). Tag-in-data
// self-validates; bounded poll + atomic fallback guarantees progress.
// Self-gating: a block's hsm slots for its own values can only be
// overwritten after its own publishes (data-dependent on the ho reads).
// ---------------------------------------------------------------------------
__global__ __launch_bounds__(512) void gru_kernel(
    const float* __restrict__ gi,    // [BS][3H]
    const float* __restrict__ w_hh,  // [3H][H]
    const float* __restrict__ b_hh,  // [3H]
    float* __restrict__ states,      // [BS][H]
    unsigned long long* __restrict__ hb)  // [2 parity][2 batch][Hd]
{
  __shared__ float hsm[Hd];          // this batch's h(t-1)
  const int bid = blockIdx.x, tid = threadIdx.x;
  const int lane = tid & 63, wv = tid >> 6;
  const int b  = bid >> 5;           // batch group
  const int gb = bid & 31;           // block index within group
  const int j0 = gb * 32 + wv * 4;   // first of this wave's 4 h-indices

  // --- w_hh rows (3 gates x 4 h-idx) into registers, lane-sliced (16 ea) ---
  f32x4 wf[12][4];
  #pragma unroll
  for (int q = 0; q < 4; ++q)
    #pragma unroll
    for (int g = 0; g < 3; ++g)
      #pragma unroll
      for (int c = 0; c < 4; ++c)
        wf[q * 3 + g][c] = *reinterpret_cast<const f32x4*>(
            w_hh + (size_t)(g * Hd + j0 + q) * Hd + lane * 4 + c * 256);

  float bias[12], gpre[12];
  if (lane == 0) {
    #pragma unroll
    for (int q = 0; q < 4; ++q)
      #pragma unroll
      for (int g = 0; g < 3; ++g) {
        bias[q * 3 + g] = b_hh[g * Hd + j0 + q];
        gpre[q * 3 + g] = gi[((size_t)b * Sd) * 3 * Hd + g * Hd + j0 + q];
      }
  }

  for (int i = tid; i < Hd; i += 512) hsm[i] = 0.f;
  __syncthreads();

  const int slot0 = tid * 2;         // this thread's 2 poll slots in [Hd]

  for (int t = 0; t < Sd; ++t) {
    // ---- matvec: 12 dot-1024 per wave, weights in regs, h from LDS ----
    float d[12];
    #pragma unroll
    for (int i = 0; i < 12; ++i) d[i] = 0.f;
    #pragma unroll
    for (int c = 0; c < 4; ++c) {
      f32x4 hv = *reinterpret_cast<const f32x4*>(&hsm[lane * 4 + c * 256]);
      #pragma unroll
      for (int i = 0; i < 12; ++i)
        d[i] += wf[i][c].x * hv.x + wf[i][c].y * hv.y
              + wf[i][c].z * hv.z + wf[i][c].w * hv.w;
    }
    #pragma unroll
    for (int off = 32; off > 0; off >>= 1)
      #pragma unroll
      for (int i = 0; i < 12; ++i)
        d[i] += __shfl_xor(d[i], off, 64);

    // all threads done reading hsm for this step before anyone overwrites it
    __syncthreads();

    const unsigned tagu = (unsigned)(t + 1);
    const unsigned long long tag = (unsigned long long)(t + 1);
    const int par = (t + 1) & 1;
    unsigned long long* hbp = hb + ((size_t)par * 2 + b) * Hd;

    if (lane == 0) {
      float hn[4];
      #pragma unroll
      for (int q = 0; q < 4; ++q) {
        const float ho = hsm[j0 + q];
        float r = sigmoidf_(gpre[q * 3 + 0] + d[q * 3 + 0] + bias[q * 3 + 0]);
        float z = sigmoidf_(gpre[q * 3 + 1] + d[q * 3 + 1] + bias[q * 3 + 1]);
        float n = tanhf(gpre[q * 3 + 2] + r * (d[q * 3 + 2] + bias[q * 3 + 2]));
        hn[q] = (1.f - z) * n + z * ho;
        __hip_atomic_store(&hbp[j0 + q],
                           (tag << 32) | (unsigned long long)__float_as_uint(hn[q]),
                           __ATOMIC_RELAXED, __HIP_MEMORY_SCOPE_AGENT);
      }
      f32x4 sv; sv.x = hn[0]; sv.y = hn[1]; sv.z = hn[2]; sv.w = hn[3];
      *reinterpret_cast<f32x4*>(states + ((size_t)b * Sd + t) * Hd + j0) = sv;
      // prefetch gi for t+1 (overlaps the poll below)
      const int tn = (t + 1 < Sd) ? (t + 1) : t;
      #pragma unroll
      for (int q = 0; q < 4; ++q)
        #pragma unroll
        for (int g = 0; g < 3; ++g)
          gpre[q * 3 + g] = gi[((size_t)b * Sd + tn) * 3 * Hd + g * Hd + j0 + q];
    }

    if (t + 1 < Sd) {
      float v0 = 0, v1 = 0;
      bool done = false;
      for (int rounds = 0; rounds < 8192 && !done; ++rounds) {
        u32x4 a;
        poll2_coherent(&hbp[slot0], a);
        if (a[1] == tagu && a[3] == tagu) {
          v0 = __uint_as_float(a[0]); v1 = __uint_as_float(a[2]);
          done = true;
        } else if (rounds >= 4) {
          __builtin_amdgcn_s_sleep(1);   // pace stragglers
        }
      }
      if (!done) {
        // guaranteed-progress fallback: 8B atomic loads (proven path)
        bool f0 = false, f1 = false;
        do {
          unsigned long long x0, x1;
          if (!f0) x0 = __hip_atomic_load(&hbp[slot0 + 0], __ATOMIC_RELAXED, __HIP_MEMORY_SCOPE_AGENT);
          if (!f1) x1 = __hip_atomic_load(&hbp[slot0 + 1], __ATOMIC_RELAXED, __HIP_MEMORY_SCOPE_AGENT);
          if (!f0 && (x0 >> 32) == tag) { v0 = __uint_as_float((unsigned)x0); f0 = true; }
          if (!f1 && (x1 >> 32) == tag) { v1 = __uint_as_float((unsigned)x1); f1 = true; }
        } while (!(f0 && f1));
      }
      hsm[slot0]     = v0;
      hsm[slot0 + 1] = v1;
    }
    __syncthreads();
  }
}

// ---------------------------------------------------------------------------
__global__ __launch_bounds__(128) void embed_kernel(
    const int* __restrict__ ids, const float* __restrict__ emb, float* __restrict__ x)
{
  const int row = blockIdx.x;
  const int tok = ids[row];
  reinterpret_cast<f32x4*>(x)[(size_t)row * (Ed / 4) + threadIdx.x] =
      reinterpret_cast<const f32x4*>(emb)[(size_t)tok * (Ed / 4) + threadIdx.x];
}

__global__ __launch_bounds__(256) void gate_kernel(
    const float* __restrict__ states, const float* __restrict__ wg,
    const float* __restrict__ bg, float* __restrict__ gate)
{
  const int row = blockIdx.x * 4 + (threadIdx.x >> 6);
  const int lane = threadIdx.x & 63;
  float s = 0;
  for (int k = lane; k < Hd; k += 64) s += states[(size_t)row * Hd + k] * wg[k];
  #pragma unroll
  for (int off = 32; off > 0; off >>= 1) s += __shfl_down(s, off, 64);
  if (lane == 0) gate[row] = sigmoidf_(s + bg[0]);
}

__global__ __launch_bounds__(256) void attn_kernel(
    const float* __restrict__ q, const float* __restrict__ k,
    const float* __restrict__ v, float* __restrict__ ctx)
{
  const int row = blockIdx.x;
  const int b = row >> 11, qi = row & (Sd - 1);
  const int tid = threadIdx.x, lane = tid & 63, wv = tid >> 6;
  __shared__ float qs[MDd];
  __shared__ float sc[Wd];
  qs[tid] = q[(size_t)row * MDd + tid];
  __syncthreads();
  const int lo = (qi > Wd) ? (qi - Wd) : 0;
  const int len = qi - lo;
  for (int jj = wv; jj < len; jj += 4) {
    const float* kr = k + (size_t)(b * Sd + lo + jj) * MDd;
    f32x4 kv = *reinterpret_cast<const f32x4*>(kr + lane * 4);
    f32x4 qv = *reinterpret_cast<const f32x4*>(&qs[lane * 4]);
    float s = kv.x * qv.x + kv.y * qv.y + kv.z * qv.z + kv.w * qv.w;
    #pragma unroll
    for (int off = 32; off > 0; off >>= 1) s += __shfl_down(s, off, 64);
    if (lane == 0) sc[jj] = s * 0.0625f;
  }
  __syncthreads();
  if (wv == 0 && len > 0) {
    float m = -3.4e38f;
    for (int jj = lane; jj < len; jj += 64) m = fmaxf(m, sc[jj]);
    #pragma unroll
    for (int off = 32; off > 0; off >>= 1) m = fmaxf(m, __shfl_xor(m, off, 64));
    float ssum = 0;
    for (int jj = lane; jj < len; jj += 64) { float e = expf(sc[jj] - m); sc[jj] = e; ssum += e; }
    #pragma unroll
    for (int off = 32; off > 0; off >>= 1) ssum += __shfl_xor(ssum, off, 64);
    const float inv = 1.f / ssum;
    for (int jj = lane; jj < len; jj += 64) sc[jj] *= inv;
  }
  __syncthreads();
  #pragma unroll
  for (int e0 = 0; e0 < Ed; e0 += 256) {
    const int e = e0 + tid;
    float a = 0;
    for (int jj = 0; jj < len; ++jj)
      a += sc[jj] * v[(size_t)(b * Sd + lo + jj) * Ed + e];
    ctx[(size_t)row * Ed + e] = a;
  }
}

__global__ __launch_bounds__(256) void fuse_kernel(
    float* __restrict__ bf, const float* __restrict__ ctx,
    const float* __restrict__ gate, const float* __restrict__ msp)
{
  const size_t i = (size_t)blockIdx.x * 256 + threadIdx.x;
  const int r = (int)(i >> 9);
  bf[i] += gate[r] * msp[0] * ctx[i];
}

// ---------------------------------------------------------------------------
extern "C" void kernel_launch(void* const* d_in, const int* in_sizes, int n_in,
                              void* d_out, int out_size, void* d_ws, size_t ws_size,
                              hipStream_t stream)
{
  const int*   ids    = (const int*)d_in[0];
  const int*   untied = (const int*)d_in[1];
  const float* emb    = (const float*)d_in[2];
  const float* w_ih   = (const float*)d_in[3];
  const float* w_hh   = (const float*)d_in[4];
  const float* b_ih   = (const float*)d_in[5];
  const float* b_hh   = (const float*)d_in[6];
  const float* wq     = (const float*)d_in[7];
  const float* bq     = (const float*)d_in[8];
  const float* wk     = (const float*)d_in[9];
  const float* bk     = (const float*)d_in[10];
  const float* wv     = (const float*)d_in[11];
  const float* bv     = (const float*)d_in[12];
  const float* wg     = (const float*)d_in[13];
  const float* bg     = (const float*)d_in[14];
  const float* w_fc   = (const float*)d_in[15];
  const float* b_fc   = (const float*)d_in[16];
  const float* w_hp   = (const float*)d_in[17];
  const float* b_hp   = (const float*)d_in[18];
  const float* out_b  = (const float*)d_in[19];
  const float* w_ph   = (const float*)d_in[20];
  const float* b_ph   = (const float*)d_in[21];
  const float* msc    = (const float*)d_in[22];
  float* out = (float*)d_out;

  float* ws      = (float*)d_ws;
  float* gi      = ws;                               // [BS][3H]
  float* states  = gi + (size_t)BS * 3 * Hd;         // [BS][H]
  float* featb   = states + (size_t)BS * Hd;         // x, then base_feat [BS][E]
  float* hfb     = featb + (size_t)BS * Ed;          // hf [BS][4E], later q/k/v/ctx/gate
  unsigned long long* hb = (unsigned long long*)(hfb + (size_t)BS * 4 * Ed); // [2][2][Hd]

  float* qb    = hfb;
  float* kb    = qb + (size_t)BS * MDd;
  float* vb    = kb + (size_t)BS * MDd;
  float* ctxb  = vb + (size_t)BS * Ed;
  float* gateb = ctxb + (size_t)BS * Ed;

  hipMemsetAsync(hb, 0, 2 * 2 * Hd * sizeof(unsigned long long), stream);

  // x = emb[ids]
  embed_kernel<<<BS, 128, 0, stream>>>(ids, emb, featb);
  // gi = x @ w_ih^T + b_ih
  gemm_bt<0><<<dim3(3 * Hd / 128, BS / 128), 256, 0, stream>>>(
      featb, w_ih, b_ih, gi, BS, 3 * Hd, Ed, 3 * Hd, nullptr, nullptr, nullptr);
  // states = GRU(gi)
  gru_kernel<<<GBLK, 512, 0, stream>>>(gi, w_hh, b_hh, states, hb);
  // hf = relu(states @ w_fc^T + b_fc)^2
  gemm_bt<1><<<dim3(4 * Ed / 128, BS / 128), 256, 0, stream>>>(
      states, w_fc, b_fc, hfb, BS, 4 * Ed, Hd, 4 * Ed, nullptr, nullptr, nullptr);
  // base_feat = hf @ w_hp^T + b_hp
  gemm_bt<0><<<dim3(Ed / 128, BS / 128), 256, 0, stream>>>(
      hfb, w_hp, b_hp, featb, BS, Ed, 4 * Ed, Ed, nullptr, nullptr, nullptr);
  // base_logits = base_feat @ emb^T + out_bias  -> d_out
  gemm_bt<0><<<dim3(Vd / 128, BS / 128), 256, 0, stream>>>(
      featb, emb, out_b, out, BS, Vd, Ed, Vd, nullptr, nullptr, nullptr);
  // q,k,v
  gemm_bt<0><<<dim3(MDd / 128, BS / 128), 256, 0, stream>>>(
      states, wq, bq, qb, BS, MDd, Hd, MDd, nullptr, nullptr, nullptr);
  gemm_bt<0><<<dim3(MDd / 128, BS / 128), 256, 0, stream>>>(
      states, wk, bk, kb, BS, MDd, Hd, MDd, nullptr, nullptr, nullptr);
  gemm_bt<0><<<dim3(Ed / 128, BS / 128), 256, 0, stream>>>(
      states, wv, bv, vb, BS, Ed, Hd, Ed, nullptr, nullptr, nullptr);
  // gate
  gate_kernel<<<BS / 4, 256, 0, stream>>>(states, wg, bg, gateb);
  // ctx = windowed attention
  attn_kernel<<<BS, 256, 0, stream>>>(qb, kb, vb, ctxb);
  // base_feat += gate * ms * ctx   (in place)
  fuse_kernel<<<(BS * Ed) / 256, 256, 0, stream>>>(featb, ctxb, gateb, msc);
  // scatter: d_out[r, untied[c]] += fused_feat @ w_ph^T + (1+gate*ms)*b_ph
  gemm_bt<3><<<dim3(Pd / 128, BS / 128), 256, 0, stream>>>(
      featb, w_ph, b_ph, out, BS, Pd, Ed, Vd, gateb, msc, untied);
}

// Round 7
// 10123.507 us; speedup vs baseline: 1.6025x; 1.6025x over previous
//
#include <hip/hip_runtime.h>
#include <math.h>

typedef __attribute__((ext_vector_type(4))) float f32x4;
typedef __attribute__((ext_vector_type(2))) float f32x2;
typedef __attribute__((ext_vector_type(8))) __bf16 bf16x8;
typedef __attribute__((ext_vector_type(4))) __bf16 bf16x4;
typedef __attribute__((ext_vector_type(4))) unsigned int u32x4;

#define DI __device__ __forceinline__

constexpr int Bd = 2, Sd = 2048, Vd = 32000, Ed = 512, Hd = 1024, MDd = 256, Pd = 4096, Wd = 128;
constexpr int BS = Bd * Sd;          // 4096 rows
constexpr int GBLK = 256;            // GRU blocks: 128 per batch group

DI float sigmoidf_(float x) { return 1.0f / (1.0f + expf(-x)); }

// ---------------------------------------------------------------------------
// Generic GEMM: C[M,N] = epi( A[M,K] * Wt[N,K]^T + bias )
// EPI 0: C = acc + bias
// EPI 1: C = (relu(acc + bias))^2
// EPI 3: atomicAdd(C[r, untied[c]], acc + (1 + gate[r]*ms) * bias[c])
// ---------------------------------------------------------------------------
template<int EPI>
__global__ __launch_bounds__(256) void gemm_bt(
    const float* __restrict__ A, const float* __restrict__ Wt,
    const float* __restrict__ bias, float* __restrict__ C,
    int M, int N, int K, int ldc,
    const float* __restrict__ gate, const float* __restrict__ msp,
    const int* __restrict__ untied)
{
  __shared__ __bf16 As[128][40];   // +8 pad: 80B row stride, 16B-aligned
  __shared__ __bf16 Bs[128][40];
  const int tid  = threadIdx.x;
  const int lane = tid & 63, wv = tid >> 6;
  const int m0 = blockIdx.y * 128, n0 = blockIdx.x * 128;
  const int wrow = (wv >> 1) * 64, wcol = (wv & 1) * 64;

  f32x4 acc[4][4] = {};

  const int sr  = tid >> 3;          // 0..31
  const int sc4 = (tid & 7) << 2;    // 0..28 step 4
  const int nk  = K >> 5;

  for (int kt = 0; kt < nk; ++kt) {
    const int k0 = kt << 5;
    __syncthreads();
    #pragma unroll
    for (int i = 0; i < 4; ++i) {
      const int r = sr + 32 * i;
      f32x4 av = *reinterpret_cast<const f32x4*>(A  + (size_t)(m0 + r) * K + k0 + sc4);
      f32x4 bv = *reinterpret_cast<const f32x4*>(Wt + (size_t)(n0 + r) * K + k0 + sc4);
      bf16x4 ah, bh;
      ah.x = (__bf16)av.x; ah.y = (__bf16)av.y; ah.z = (__bf16)av.z; ah.w = (__bf16)av.w;
      bh.x = (__bf16)bv.x; bh.y = (__bf16)bv.y; bh.z = (__bf16)bv.z; bh.w = (__bf16)bv.w;
      *reinterpret_cast<bf16x4*>(&As[r][sc4]) = ah;
      *reinterpret_cast<bf16x4*>(&Bs[r][sc4]) = bh;
    }
    __syncthreads();

    bf16x8 af[4], bfr[4];
    #pragma unroll
    for (int t2 = 0; t2 < 4; ++t2) {
      af[t2]  = *reinterpret_cast<const bf16x8*>(&As[wrow + t2 * 16 + (lane & 15)][(lane >> 4) * 8]);
      bfr[t2] = *reinterpret_cast<const bf16x8*>(&Bs[wcol + t2 * 16 + (lane & 15)][(lane >> 4) * 8]);
    }
    #pragma unroll
    for (int mi = 0; mi < 4; ++mi)
      #pragma unroll
      for (int ni = 0; ni < 4; ++ni)
        acc[mi][ni] = __builtin_amdgcn_mfma_f32_16x16x32_bf16(af[mi], bfr[ni], acc[mi][ni], 0, 0, 0);
  }

  const float ms = (EPI == 3) ? msp[0] : 0.f;
  #pragma unroll
  for (int mi = 0; mi < 4; ++mi) {
    #pragma unroll
    for (int ni = 0; ni < 4; ++ni) {
      const int cc = n0 + wcol + ni * 16 + (lane & 15);
      const float bv = bias ? bias[cc] : 0.f;
      #pragma unroll
      for (int rg = 0; rg < 4; ++rg) {
        const int rr = m0 + wrow + mi * 16 + (lane >> 4) * 4 + rg;
        const float v = acc[mi][ni][rg];
        if (EPI == 0) {
          C[(size_t)rr * ldc + cc] = v + bv;
        } else if (EPI == 1) {
          float u = fmaxf(v + bv, 0.f);
          C[(size_t)rr * ldc + cc] = u * u;
        } else {
          float g = 1.f + gate[rr] * ms;
          atomicAdd(&C[(size_t)rr * ldc + untied[cc]], v + g * bv);
        }
      }
    }
  }
}

// Device-coherent 16B poll: sc0 (L1 bypass) + sc1 (L2 bypass) reads the
// coherence point where producers' relaxed agent atomic stores land.
DI void poll2_coherent(const unsigned long long* p, u32x4& a) {
  asm volatile("global_load_dwordx4 %0, %1, off sc0 sc1\n\t"
               "s_waitcnt vmcnt(0)"
               : "=&v"(a) : "v"(p) : "memory");
}

// ---------------------------------------------------------------------------
// Persistent GRU v7: 256 blocks x 512 threads, two independent groups of 128
// (one per batch). Wave wv of group-block gb owns ONE h-index j = gb*8+wv;
// its 3 w_hh rows live in registers. Critical-path minimized:
//  - gate nonlinearity wave-parallel (both sigmoids concurrent on lanes 0/1,
//    tanh broadcast) instead of lane-0 serial
//  - gi pregates loaded COALESCED (24 threads, 3x32B) into parity-buffered LDS
//  - ONE barrier per step (publish-before-hsm-write makes the second redundant)
//  - states written coalesced by one writer block per group from poll values
// Sync = proven v5 path: tag-in-data u64, relaxed agent atomic stores,
// 16B sc0+sc1 poll loads, parity double-buffer, bounded poll + atomic
// fallback for guaranteed progress.
// ---------------------------------------------------------------------------
__global__ __launch_bounds__(512) void gru_kernel(
    const float* __restrict__ gi,    // [BS][3H]
    const float* __restrict__ w_hh,  // [3H][H]
    const float* __restrict__ b_hh,  // [3H]
    float* __restrict__ states,      // [BS][H]
    unsigned long long* __restrict__ hb)  // [2 parity][2 batch][Hd]
{
  __shared__ float hsm[Hd];          // this batch's h(t-1)
  __shared__ float gpre_sm[2][24];   // parity-buffered pregates for 8 h-idx
  const int bid = blockIdx.x, tid = threadIdx.x;
  const int lane = tid & 63, wv = tid >> 6;
  const int b  = bid >> 7;           // batch group
  const int gb = bid & 127;          // block index within group
  const int j  = gb * 8 + wv;        // this wave's h index

  // --- w_hh rows (r,z,n for j) into registers, lane-sliced (16 floats ea) ---
  f32x4 wr[4], wz[4], wn[4];
  #pragma unroll
  for (int c = 0; c < 4; ++c) {
    const int k = lane * 4 + c * 256;
    wr[c] = *reinterpret_cast<const f32x4*>(w_hh + (size_t)(0 * Hd + j) * Hd + k);
    wz[c] = *reinterpret_cast<const f32x4*>(w_hh + (size_t)(1 * Hd + j) * Hd + k);
    wn[c] = *reinterpret_cast<const f32x4*>(w_hh + (size_t)(2 * Hd + j) * Hd + k);
  }
  const float br = b_hh[j], bz = b_hh[Hd + j], bn = b_hh[2 * Hd + j];

  for (int i = tid; i < Hd; i += 512) hsm[i] = 0.f;
  if (tid < 24) {
    const int g = tid >> 3, o = tid & 7;
    gpre_sm[0][tid] = gi[(size_t)b * Sd * 3 * Hd + g * Hd + gb * 8 + o];
  }
  __syncthreads();

  const int slot0 = tid * 2;         // this thread's 2 poll slots in [Hd]
  const bool writer = (gb == 0);

  for (int t = 0; t < Sd; ++t) {
    // ---- matvec: 3 dot-1024 per wave, weights in regs, h from LDS ----
    float d0 = 0, d1 = 0, d2 = 0;
    #pragma unroll
    for (int c = 0; c < 4; ++c) {
      f32x4 hv = *reinterpret_cast<const f32x4*>(&hsm[lane * 4 + c * 256]);
      d0 += wr[c].x*hv.x + wr[c].y*hv.y + wr[c].z*hv.z + wr[c].w*hv.w;
      d1 += wz[c].x*hv.x + wz[c].y*hv.y + wz[c].z*hv.z + wz[c].w*hv.w;
      d2 += wn[c].x*hv.x + wn[c].y*hv.y + wn[c].z*hv.z + wn[c].w*hv.w;
    }
    #pragma unroll
    for (int off = 32; off > 0; off >>= 1) {
      d0 += __shfl_xor(d0, off, 64);
      d1 += __shfl_xor(d1, off, 64);
      d2 += __shfl_xor(d2, off, 64);
    }

    const unsigned tagu = (unsigned)(t + 1);
    const unsigned long long tag = (unsigned long long)(t + 1);
    const int par = (t + 1) & 1;
    unsigned long long* hbp = hb + ((size_t)par * 2 + b) * Hd;

    // ---- gate: wave-parallel (lanes 0/1 sigmoids concurrent, tanh bcast) ----
    const float pgr = gpre_sm[t & 1][wv];
    const float pgz = gpre_sm[t & 1][8 + wv];
    const float pgn = gpre_sm[t & 1][16 + wv];
    const float a  = (lane == 0) ? (pgr + d0 + br) : (pgz + d1 + bz);
    const float sg = sigmoidf_(a);
    const float r  = __shfl(sg, 0, 64);
    const float z  = __shfl(sg, 1, 64);
    const float n  = tanhf(pgn + r * (d2 + bn));
    const float ho = hsm[j];
    const float h  = (1.f - z) * n + z * ho;
    if (lane == 0)
      __hip_atomic_store(&hbp[j],
                         (tag << 32) | (unsigned long long)__float_as_uint(h),
                         __ATOMIC_RELAXED, __HIP_MEMORY_SCOPE_AGENT);

    // ---- coalesced gi prefetch for t+1 into the other parity buffer ----
    if (tid < 24) {
      const int g = tid >> 3, o = tid & 7;
      const int tn = (t + 1 < Sd) ? (t + 1) : t;
      gpre_sm[par][tid] = gi[((size_t)b * Sd + tn) * 3 * Hd + g * Hd + gb * 8 + o];
    }

    if (t + 1 < Sd || writer) {
      // ---- poll own-batch slots: one 16B device-coherent load per thread ----
      float v0 = 0, v1 = 0;
      bool done = false;
      for (int rounds = 0; rounds < 16384 && !done; ++rounds) {
        u32x4 a4;
        poll2_coherent(&hbp[slot0], a4);
        if (a4[1] == tagu && a4[3] == tagu) {
          v0 = __uint_as_float(a4[0]); v1 = __uint_as_float(a4[2]);
          done = true;
        } else if (rounds >= 6) {
          __builtin_amdgcn_s_sleep(1);   // pace stragglers
        }
      }
      if (!done) {
        // guaranteed-progress fallback: 8B atomic loads (proven path)
        bool f0 = false, f1 = false;
        do {
          unsigned long long x0, x1;
          if (!f0) x0 = __hip_atomic_load(&hbp[slot0 + 0], __ATOMIC_RELAXED, __HIP_MEMORY_SCOPE_AGENT);
          if (!f1) x1 = __hip_atomic_load(&hbp[slot0 + 1], __ATOMIC_RELAXED, __HIP_MEMORY_SCOPE_AGENT);
          if (!f0 && (x0 >> 32) == tag) { v0 = __uint_as_float((unsigned)x0); f0 = true; }
          if (!f1 && (x1 >> 32) == tag) { v1 = __uint_as_float((unsigned)x1); f1 = true; }
        } while (!(f0 && f1));
      }
      if (writer) {
        f32x2 sv; sv.x = v0; sv.y = v1;
        *reinterpret_cast<f32x2*>(states + ((size_t)b * Sd + t) * Hd + slot0) = sv;
      }
      hsm[slot0]     = v0;
      hsm[slot0 + 1] = v1;
    }
    __syncthreads();   // hsm fully updated before next matvec
  }
}

// ---------------------------------------------------------------------------
__global__ __launch_bounds__(128) void embed_kernel(
    const int* __restrict__ ids, const float* __restrict__ emb, float* __restrict__ x)
{
  const int row = blockIdx.x;
  const int tok = ids[row];
  reinterpret_cast<f32x4*>(x)[(size_t)row * (Ed / 4) + threadIdx.x] =
      reinterpret_cast<const f32x4*>(emb)[(size_t)tok * (Ed / 4) + threadIdx.x];
}

__global__ __launch_bounds__(256) void gate_kernel(
    const float* __restrict__ states, const float* __restrict__ wg,
    const float* __restrict__ bg, float* __restrict__ gate)
{
  const int row = blockIdx.x * 4 + (threadIdx.x >> 6);
  const int lane = threadIdx.x & 63;
  float s = 0;
  for (int k = lane; k < Hd; k += 64) s += states[(size_t)row * Hd + k] * wg[k];
  #pragma unroll
  for (int off = 32; off > 0; off >>= 1) s += __shfl_down(s, off, 64);
  if (lane == 0) gate[row] = sigmoidf_(s + bg[0]);
}

__global__ __launch_bounds__(256) void attn_kernel(
    const float* __restrict__ q, const float* __restrict__ k,
    const float* __restrict__ v, float* __restrict__ ctx)
{
  const int row = blockIdx.x;
  const int b = row >> 11, qi = row & (Sd - 1);
  const int tid = threadIdx.x, lane = tid & 63, wv = tid >> 6;
  __shared__ float qs[MDd];
  __shared__ float sc[Wd];
  qs[tid] = q[(size_t)row * MDd + tid];
  __syncthreads();
  const int lo = (qi > Wd) ? (qi - Wd) : 0;
  const int len = qi - lo;
  for (int jj = wv; jj < len; jj += 4) {
    const float* kr = k + (size_t)(b * Sd + lo + jj) * MDd;
    f32x4 kv = *reinterpret_cast<const f32x4*>(kr + lane * 4);
    f32x4 qv = *reinterpret_cast<const f32x4*>(&qs[lane * 4]);
    float s = kv.x * qv.x + kv.y * qv.y + kv.z * qv.z + kv.w * qv.w;
    #pragma unroll
    for (int off = 32; off > 0; off >>= 1) s += __shfl_down(s, off, 64);
    if (lane == 0) sc[jj] = s * 0.0625f;
  }
  __syncthreads();
  if (wv == 0 && len > 0) {
    float m = -3.4e38f;
    for (int jj = lane; jj < len; jj += 64) m = fmaxf(m, sc[jj]);
    #pragma unroll
    for (int off = 32; off > 0; off >>= 1) m = fmaxf(m, __shfl_xor(m, off, 64));
    float ssum = 0;
    for (int jj = lane; jj < len; jj += 64) { float e = expf(sc[jj] - m); sc[jj] = e; ssum += e; }
    #pragma unroll
    for (int off = 32; off > 0; off >>= 1) ssum += __shfl_xor(ssum, off, 64);
    const float inv = 1.f / ssum;
    for (int jj = lane; jj < len; jj += 64) sc[jj] *= inv;
  }
  __syncthreads();
  #pragma unroll
  for (int e0 = 0; e0 < Ed; e0 += 256) {
    const int e = e0 + tid;
    float a = 0;
    for (int jj = 0; jj < len; ++jj)
      a += sc[jj] * v[(size_t)(b * Sd + lo + jj) * Ed + e];
    ctx[(size_t)row * Ed + e] = a;
  }
}

__global__ __launch_bounds__(256) void fuse_kernel(
    float* __restrict__ bf, const float* __restrict__ ctx,
    const float* __restrict__ gate, const float* __restrict__ msp)
{
  const size_t i = (size_t)blockIdx.x * 256 + threadIdx.x;
  const int r = (int)(i >> 9);
  bf[i] += gate[r] * msp[0] * ctx[i];
}

// ---------------------------------------------------------------------------
extern "C" void kernel_launch(void* const* d_in, const int* in_sizes, int n_in,
                              void* d_out, int out_size, void* d_ws, size_t ws_size,
                              hipStream_t stream)
{
  const int*   ids    = (const int*)d_in[0];
  const int*   untied = (const int*)d_in[1];
  const float* emb    = (const float*)d_in[2];
  const float* w_ih   = (const float*)d_in[3];
  const float* w_hh   = (const float*)d_in[4];
  const float* b_ih   = (const float*)d_in[5];
  const float* b_hh   = (const float*)d_in[6];
  const float* wq     = (const float*)d_in[7];
  const float* bq     = (const float*)d_in[8];
  const float* wk     = (const float*)d_in[9];
  const float* bk     = (const float*)d_in[10];
  const float* wv     = (const float*)d_in[11];
  const float* bv     = (const float*)d_in[12];
  const float* wg     = (const float*)d_in[13];
  const float* bg     = (const float*)d_in[14];
  const float* w_fc   = (const float*)d_in[15];
  const float* b_fc   = (const float*)d_in[16];
  const float* w_hp   = (const float*)d_in[17];
  const float* b_hp   = (const float*)d_in[18];
  const float* out_b  = (const float*)d_in[19];
  const float* w_ph   = (const float*)d_in[20];
  const float* b_ph   = (const float*)d_in[21];
  const float* msc    = (const float*)d_in[22];
  float* out = (float*)d_out;

  float* ws      = (float*)d_ws;
  float* gi      = ws;                               // [BS][3H]
  float* states  = gi + (size_t)BS * 3 * Hd;         // [BS][H]
  float* featb   = states + (size_t)BS * Hd;         // x, then base_feat [BS][E]
  float* hfb     = featb + (size_t)BS * Ed;          // hf [BS][4E], later q/k/v/ctx/gate
  unsigned long long* hb = (unsigned long long*)(hfb + (size_t)BS * 4 * Ed); // [2][2][Hd]

  float* qb    = hfb;
  float* kb    = qb + (size_t)BS * MDd;
  float* vb    = kb + (size_t)BS * MDd;
  float* ctxb  = vb + (size_t)BS * Ed;
  float* gateb = ctxb + (size_t)BS * Ed;

  hipMemsetAsync(hb, 0, 2 * 2 * Hd * sizeof(unsigned long long), stream);

  // x = emb[ids]
  embed_kernel<<<BS, 128, 0, stream>>>(ids, emb, featb);
  // gi = x @ w_ih^T + b_ih
  gemm_bt<0><<<dim3(3 * Hd / 128, BS / 128), 256, 0, stream>>>(
      featb, w_ih, b_ih, gi, BS, 3 * Hd, Ed, 3 * Hd, nullptr, nullptr, nullptr);
  // states = GRU(gi)
  gru_kernel<<<GBLK, 512, 0, stream>>>(gi, w_hh, b_hh, states, hb);
  // hf = relu(states @ w_fc^T + b_fc)^2
  gemm_bt<1><<<dim3(4 * Ed / 128, BS / 128), 256, 0, stream>>>(
      states, w_fc, b_fc, hfb, BS, 4 * Ed, Hd, 4 * Ed, nullptr, nullptr, nullptr);
  // base_feat = hf @ w_hp^T + b_hp
  gemm_bt<0><<<dim3(Ed / 128, BS / 128), 256, 0, stream>>>(
      hfb, w_hp, b_hp, featb, BS, Ed, 4 * Ed, Ed, nullptr, nullptr, nullptr);
  // base_logits = base_feat @ emb^T + out_bias  -> d_out
  gemm_bt<0><<<dim3(Vd / 128, BS / 128), 256, 0, stream>>>(
      featb, emb, out_b, out, BS, Vd, Ed, Vd, nullptr, nullptr, nullptr);
  // q,k,v
  gemm_bt<0><<<dim3(MDd / 128, BS / 128), 256, 0, stream>>>(
      states, wq, bq, qb, BS, MDd, Hd, MDd, nullptr, nullptr, nullptr);
  gemm_bt<0><<<dim3(MDd / 128, BS / 128), 256, 0, stream>>>(
      states, wk, bk, kb, BS, MDd, Hd, MDd, nullptr, nullptr, nullptr);
  gemm_bt<0><<<dim3(Ed / 128, BS / 128), 256, 0, stream>>>(
      states, wv, bv, vb, BS, Ed, Hd, Ed, nullptr, nullptr, nullptr);
  // gate
  gate_kernel<<<BS / 4, 256, 0, stream>>>(states, wg, bg, gateb);
  // ctx = windowed attention
  attn_kernel<<<BS, 256, 0, stream>>>(qb, kb, vb, ctxb);
  // base_feat += gate * ms * ctx   (in place)
  fuse_kernel<<<(BS * Ed) / 256, 256, 0, stream>>>(featb, ctxb, gateb, msc);
  // scatter: d_out[r, untied[c]] += fused_feat @ w_ph^T + (1+gate*ms)*b_ph
  gemm_bt<3><<<dim3(Pd / 128, BS / 128), 256, 0, stream>>>(
      featb, w_ph, b_ph, out, BS, Pd, Ed, Vd, gateb, msc, untied);
}